// Round 1
// 885.430 us; speedup vs baseline: 1.2377x; 1.2377x over previous
//
#include <hip/hip_runtime.h>

#define US unsigned short

typedef short bf16x8 __attribute__((ext_vector_type(8)));
typedef float f32x4 __attribute__((ext_vector_type(4)));

__device__ __forceinline__ float b2f(US u) {
  union { unsigned u; float f; } x; x.u = ((unsigned)u) << 16; return x.f;
}
__device__ __forceinline__ US f2b(float f) {
  union { float f; unsigned u; } x; x.f = f;
  unsigned r = x.u + 0x7FFFu + ((x.u >> 16) & 1u);
  return (US)(r >> 16);
}
__device__ __forceinline__ float lk(float v) { return v >= 0.f ? v : 0.2f * v; }

// flag-dependent input read: fl=1 -> buffers are float32, fl=0 -> bf16
__device__ __forceinline__ float ldin(const void* p, int i, int fl) {
  return fl ? ((const float*)p)[i] : b2f(((const US*)p)[i]);
}

// ---- ws byte offsets ----
#define O_W1 0          /* bf16 [256][768]: fc1_w | fc_m_a_w | fc1_b @744 | 0 */
#define O_W2 393216     /* bf16 [256][256] alpha-folded */
#define O_W3 524288
#define O_W4 655360
#define O_W5 786432     /* alpha5 row-scaled */
#define O_W6 917504
#define O_B2 1048576    /* f32[256] betas */
#define O_B3 1049600
#define O_B4 1050624
#define O_B6 1051648
#define O_VD 1052672    /* f32[256][4]: {a5*wvd0, a5*wvd1, a5*wvd2, b5} */
#define O_A2 1056800    /* f32[256] alphas (temp) */
#define O_A3 1057824
#define O_A4 1058848
#define O_A6 1059872
#define O_A5 1060896
#define O_B5 1061920
#define O_FLAG 1062944  /* int: 1 = inputs are f32, 0 = bf16 */

// dtype detector: decode first 512 uint16 of x as bf16; f32 data misread as
// bf16 gives ~90% wild values (NaN / |v|>1e3 / 0<|v|<1e-3), real bf16 ~0.
__global__ void detect_dtype(const void* x, char* ws) {
  if (threadIdx.x == 0) {
    const US* p = (const US*)x;
    int wild = 0;
    for (int i = 0; i < 512; ++i) {
      float v = b2f(p[i]);
      float a = fabsf(v);
      if (!(a <= 1e3f) || (a != 0.f && a < 1e-3f)) ++wild;  // NaN fails a<=1e3
    }
    *(int*)(ws + O_FLAG) = (wild > 32) ? 1 : 0;
  }
}

struct S1Args {
  const void* z;
  const void* w[10];
  const void* b[10];
};

// vectors: [a2,a3,a4,a6, b2,b3,b4,b6, a5, b5], each out[k] = dot(z, W[k][:]) + B[k]
__global__ void setup_vec(S1Args a, char* ws) {
  const int outoff[10] = {O_A2, O_A3, O_A4, O_A6, O_B2, O_B3, O_B4, O_B6, O_A5, O_B5};
  int fl = *(const int*)(ws + O_FLAG);
  int v = blockIdx.x, k = threadIdx.x;
  const void* W = a.w[v];
  float acc = ldin(a.b[v], k, fl);
  for (int s = 0; s < 128; ++s) acc += ldin(a.z, s, fl) * ldin(W, k * 128 + s, fl);
  *(float*)(ws + outoff[v] + k * 4) = acc;
}

struct S2Args {
  const void *fc1_w, *fc1_b, *m_w, *w2, *w3, *w4, *w5, *w6, *vdw;
};

__global__ void setup_w(S2Args a, char* ws) {
  int fl = *(const int*)(ws + O_FLAG);
  int b = blockIdx.x, t = threadIdx.x;
  if (b < 256) {                       // W1p row n = b, 768 wide
    int n = b;
    US* W1p = (US*)(ws + O_W1);
    for (int i = 0; i < 3; ++i) {
      int k = t + i * 256;
      float v;
      if (k < 64) v = ldin(a.fc1_w, n * 64 + k, fl);
      else if (k < 744) v = ldin(a.m_w, n * 680 + k - 64, fl);
      else if (k == 744) v = ldin(a.fc1_b, n, fl);
      else v = 0.f;
      W1p[n * 768 + k] = f2b(v);
    }
  } else if (b < 1536) {               // layers 2,3,4,5,6 alpha-folded
    int li = (b - 256) >> 8;           // 0..4 -> W2,W3,W4,W5,W6
    int n = (b - 256) & 255;
    int k = t;
    const void* Wsrc = (li == 0) ? a.w2 : (li == 1) ? a.w3 : (li == 2) ? a.w4
                      : (li == 3) ? a.w5 : a.w6;
    const int aoff[5] = {O_A2, O_A3, O_A4, O_A5, O_A6};
    US* Wdst = (US*)(ws + O_W2 + li * 131072);
    float alpha = (li == 3) ? *(const float*)(ws + O_A5 + n * 4)     // row scale
                            : *(const float*)(ws + aoff[li] + k * 4); // col scale
    Wdst[n * 256 + k] = f2b(ldin(Wsrc, n * 256 + k, fl) * alpha);
  } else {                             // vdpack
    int n = t;
    float a5 = *(const float*)(ws + O_A5 + n * 4);
    float b5 = *(const float*)(ws + O_B5 + n * 4);
    float* vp = (float*)(ws + O_VD + n * 16);
    vp[0] = a5 * ldin(a.vdw, n * 3 + 0, fl);
    vp[1] = a5 * ldin(a.vdw, n * 3 + 1, fl);
    vp[2] = a5 * ldin(a.vdw, n * 3 + 2, fl);
    vp[3] = b5;
  }
}

// ============================================================================
// Main fused kernel, restructured:
//   2048 blocks x 256 threads, 64 rows/block. 4 waves = 4 col-groups of 64.
//   acc[4][4] f32x4 = 64 VGPRs per thread (was 128).
//   LDS 40 KB: fAct [64][256] bf16 xor-swizzled (32 KB) + layer-1 A dbuf
//   2x[64][32] (8 KB) -> >=2 blocks/CU resident (was 1 at 160 KB).
//   Layers 2..6 read W directly from global (L2-hot, 128 KB/layer shared by
//   all blocks) -> K-loop has NO barriers; 2 barriers/layer around the fAct
//   overwrite. Hot path is straight-line (no capturing lambdas) so acc
//   provably stays in registers (attacking the 468 MB/dispatch scratch
//   WRITE_SIZE seen in rocprof).
// ============================================================================

// fAct chunk address (US index): row r (0..63), chunk c = k>>3 (0..31)
#define FACT(r, c) (((r) << 8) + ((((c) ^ ((r) & 7))) << 3))
// layer-1 stage chunk address: buf 0/1, row r (0..63), chunk c (0..3)
#define STG(buf, r, c) (16384 + ((buf) << 11) + ((r) << 5) + ((((c) ^ ((r) & 3))) << 3))

#define INITZERO() do { f32x4 zz = {0.f, 0.f, 0.f, 0.f};                      \
  _Pragma("unroll") for (int rt = 0; rt < 4; ++rt)                            \
  _Pragma("unroll") for (int nt = 0; nt < 4; ++nt) acc[rt][nt] = zz; } while (0)

#define INITBETA(OFF) do {                                                    \
  _Pragma("unroll") for (int nt = 0; nt < 4; ++nt) {                          \
    float bv = *(const float*)(ws + (OFF) + ((wave << 6) + (nt << 4) + l16) * 4); \
    f32x4 tt = {bv, bv, bv, bv};                                              \
    _Pragma("unroll") for (int rt = 0; rt < 4; ++rt) acc[rt][nt] = tt; } } while (0)

// K=256 layer: A from fAct (stable in LDS, no barriers), B from global W
#define LAYER256(WP) do {                                                     \
  _Pragma("unroll 4") for (int ks = 0; ks < 8; ++ks) {                        \
    bf16x8 a[4];                                                              \
    _Pragma("unroll") for (int rt = 0; rt < 4; ++rt) {                        \
      int r = (rt << 4) + l16;                                                \
      a[rt] = *(const bf16x8*)&lds[FACT(r, (ks << 2) + q)];                   \
    }                                                                         \
    _Pragma("unroll") for (int nt = 0; nt < 4; ++nt) {                        \
      bf16x8 b = *(const bf16x8*)((WP) + ((wave << 6) + (nt << 4) + l16) * 256 + (ks << 5) + (q << 3)); \
      _Pragma("unroll") for (int rt = 0; rt < 4; ++rt)                        \
        acc[rt][nt] = __builtin_amdgcn_mfma_f32_16x16x32_bf16(a[rt], b, acc[rt][nt], 0, 0, 0); \
    }                                                                         \
  } } while (0)

// leaky-relu -> fAct (bf16, swizzled), trailing barrier
#define EPIACT() do {                                                         \
  _Pragma("unroll") for (int nt = 0; nt < 4; ++nt) {                          \
    int k = (wave << 6) + (nt << 4) + l16;                                    \
    _Pragma("unroll") for (int rt = 0; rt < 4; ++rt)                          \
    _Pragma("unroll") for (int rg = 0; rg < 4; ++rg) {                        \
      int r = (rt << 4) + (q << 2) + rg;                                      \
      lds[FACT(r, k >> 3) + (k & 7)] = f2b(lk(acc[rt][nt][rg]));              \
    } }                                                                       \
  __syncthreads(); } while (0)

// layer-1 A row chunk: x | m | bias-one | 0, converted to bf16
__device__ __forceinline__ bf16x8 loadA1(const void* __restrict__ x,
                                         const void* __restrict__ m,
                                         int fl, int g, int s, int skk) {
  int k = s * 32 + skk;
  bf16x8 v = {0, 0, 0, 0, 0, 0, 0, 0};
  if (k < 744) {
    if (fl) {
      const float* p = (k < 64) ? (const float*)x + g * 64 + k
                                : (const float*)m + g * 680 + (k - 64);
#pragma unroll
      for (int j = 0; j < 8; ++j) v[j] = (short)f2b(p[j]);
    } else {
      const US* p = (k < 64) ? (const US*)x + g * 64 + k
                             : (const US*)m + g * 680 + (k - 64);
      v = *(const bf16x8*)p;
    }
  } else if (k == 744) {
    v[0] = (short)0x3F80;  // bias multiplier 1.0
  }
  return v;
}

__global__ __launch_bounds__(256, 2) void mlp_main(
    const void* __restrict__ x, const void* __restrict__ rdir, const void* __restrict__ m,
    const void* __restrict__ wsig, const void* __restrict__ bsig,
    const void* __restrict__ wout, const void* __restrict__ bout,
    const char* __restrict__ ws, void* __restrict__ out) {
  __shared__ US lds[20480];  // 40 KB
  const int fl = *(const int*)(ws + O_FLAG);
  const int tid = threadIdx.x;
  const int wave = tid >> 6, lane = tid & 63;
  const int l16 = lane & 15, q = lane >> 4;
  const int R0 = blockIdx.x * 64;

  const US* W1p = (const US*)(ws + O_W1);
  const US* W2p = (const US*)(ws + O_W2);
  const US* W3p = (const US*)(ws + O_W3);
  const US* W4p = (const US*)(ws + O_W4);
  const US* W5p = (const US*)(ws + O_W5);
  const US* W6p = (const US*)(ws + O_W6);

  f32x4 acc[4][4];

  // ---- Layer 1: f1 = act(x@W1^T + m@Wm^T + b1), K = 768, A staged (dbuf) ----
  INITZERO();
  {
    const int srow = tid >> 2, skk = (tid & 3) << 3, g = R0 + srow;
    bf16x8 cur = loadA1(x, m, fl, g, 0, skk);
    *(bf16x8*)&lds[STG(0, srow, skk >> 3)] = cur;
#pragma unroll 1
    for (int s = 0; s < 24; ++s) {
      bf16x8 nxt;
      if (s < 23) nxt = loadA1(x, m, fl, g, s + 1, skk);
      __syncthreads();  // stage[s&1] visible; buf (s+1)&1 free to overwrite
      bf16x8 a[4];
#pragma unroll
      for (int rt = 0; rt < 4; ++rt) {
        int r = (rt << 4) + l16;
        a[rt] = *(const bf16x8*)&lds[STG(s & 1, r, q)];
      }
#pragma unroll
      for (int nt = 0; nt < 4; ++nt) {
        bf16x8 b = *(const bf16x8*)(W1p + ((wave << 6) + (nt << 4) + l16) * 768 + (s << 5) + (q << 3));
#pragma unroll
        for (int rt = 0; rt < 4; ++rt)
          acc[rt][nt] = __builtin_amdgcn_mfma_f32_16x16x32_bf16(a[rt], b, acc[rt][nt], 0, 0, 0);
      }
      if (s < 23) *(bf16x8*)&lds[STG((s + 1) & 1, srow, skk >> 3)] = nxt;
    }
  }
  EPIACT();  // writes fAct (untouched during L1) — no pre-barrier needed

  // ---- Layers 2..4 (modulated; alpha folded into W, beta via acc-init) ----
  INITBETA(O_B2); LAYER256(W2p); __syncthreads(); EPIACT();
  INITBETA(O_B3); LAYER256(W3p); __syncthreads(); EPIACT();
  INITBETA(O_B4); LAYER256(W4p); __syncthreads(); EPIACT();

  // ---- sigma head from f4 (fAct) ----
  {
    int r = tid >> 2, q4 = tid & 3, g = R0 + r;
    float sgv = 0.f;
#pragma unroll
    for (int i = 0; i < 8; ++i) {
      int c = q4 * 8 + i;
      bf16x8 av = *(const bf16x8*)&lds[FACT(r, c)];
#pragma unroll
      for (int j = 0; j < 8; ++j) sgv += b2f((US)av[j]) * ldin(wsig, c * 8 + j, fl);
    }
    sgv += __shfl_xor(sgv, 1);
    sgv += __shfl_xor(sgv, 2);
    if (q4 == 0) {
      float v = sgv + ldin(bsig, 0, fl);
      if (fl) ((float*)out)[g] = v; else ((US*)out)[g] = f2b(v);
    }
  }
  // rays into the (now idle) stage area; visible after the next barrier
  if (tid < 24) ((float*)&lds[16384])[tid] = ldin(rdir, (R0 >> 3) * 3 + tid, fl);

  // ---- Layer 5: f5 = act(a5*(f4@W5^T + vd@Wvd^T) + b5); a5 folded into W5p/vdpack ----
  INITZERO();
  LAYER256(W5p);
  __syncthreads();  // f4 reads (layer5 + sigma) done; rays visible
  {
    const float* rays = (const float*)&lds[16384];
    float ry[4][3];
#pragma unroll
    for (int rt = 0; rt < 4; ++rt) {
      int p = rt * 2 + (q >> 1);  // pixel constant across reg 0..3
      ry[rt][0] = rays[p * 3 + 0]; ry[rt][1] = rays[p * 3 + 1]; ry[rt][2] = rays[p * 3 + 2];
    }
#pragma unroll
    for (int nt = 0; nt < 4; ++nt) {
      int n = (wave << 6) + (nt << 4) + l16;
      float4 vp = *(const float4*)(ws + O_VD + n * 16);
#pragma unroll
      for (int rt = 0; rt < 4; ++rt) {
#pragma unroll
        for (int rg = 0; rg < 4; ++rg) {
          float v = acc[rt][nt][rg] + ry[rt][0] * vp.x + ry[rt][1] * vp.y + ry[rt][2] * vp.z + vp.w;
          v = lk(v);
          int r = (rt << 4) + (q << 2) + rg;
          lds[FACT(r, n >> 3) + (n & 7)] = f2b(v);
        }
      }
    }
  }
  __syncthreads();  // fAct(f5) visible

  // ---- Layer 6 ----
  INITBETA(O_B6); LAYER256(W6p); __syncthreads(); EPIACT();

  // ---- rgb head from f6 ----
  {
    int r = tid >> 2, q4 = tid & 3, g = R0 + r;
    float c0 = 0.f, c1 = 0.f, c2 = 0.f;
#pragma unroll
    for (int i = 0; i < 8; ++i) {
      int c = q4 * 8 + i;
      bf16x8 av = *(const bf16x8*)&lds[FACT(r, c)];
#pragma unroll
      for (int j = 0; j < 8; ++j) {
        float f = b2f((US)av[j]);
        int ci = c * 8 + j;
        c0 += f * ldin(wout, ci, fl);
        c1 += f * ldin(wout, 256 + ci, fl);
        c2 += f * ldin(wout, 512 + ci, fl);
      }
    }
    c0 += __shfl_xor(c0, 1); c0 += __shfl_xor(c0, 2);
    c1 += __shfl_xor(c1, 1); c1 += __shfl_xor(c1, 2);
    c2 += __shfl_xor(c2, 1); c2 += __shfl_xor(c2, 2);
    if (q4 == 0) {
      float v0 = c0 + ldin(bout, 0, fl);
      float v1 = c1 + ldin(bout, 1, fl);
      float v2 = c2 + ldin(bout, 2, fl);
      if (fl) {
        float* o = (float*)out + 131072 + g * 3;
        o[0] = v0; o[1] = v1; o[2] = v2;
      } else {
        US* o = (US*)out + 131072 + g * 3;
        o[0] = f2b(v0); o[1] = f2b(v1); o[2] = f2b(v2);
      }
    }
  }
}

extern "C" void kernel_launch(void* const* d_in, const int* in_sizes, int n_in,
                              void* d_out, int out_size, void* d_ws, size_t ws_size,
                              hipStream_t stream) {
  const void* in[37];
  for (int i = 0; i < 37 && i < n_in; ++i) in[i] = d_in[i];
  char* ws = (char*)d_ws;

  detect_dtype<<<1, 64, 0, stream>>>(in[0], ws);

  S1Args a1;
  a1.z = in[2];
  const int wi[10] = {9, 14, 19, 24, 11, 16, 21, 26, 31, 33};
  const int bi[10] = {10, 15, 20, 25, 12, 17, 22, 27, 32, 34};
  for (int i = 0; i < 10; ++i) { a1.w[i] = in[wi[i]]; a1.b[i] = in[bi[i]]; }
  setup_vec<<<10, 256, 0, stream>>>(a1, ws);

  S2Args a2{in[6], in[7], in[4], in[8], in[13], in[18], in[30], in[23], in[5]};
  setup_w<<<1537, 256, 0, stream>>>(a2, ws);

  mlp_main<<<2048, 256, 0, stream>>>(in[0], in[1], in[3], in[28], in[29], in[35], in[36],
                                     (const char*)ws, d_out);
}